// Round 10
// baseline (8159.679 us; speedup 1.0000x reference)
//
#include <hip/hip_runtime.h>
#include <stdint.h>

// LSTM(relu) persistent kernel v10: B=64,S=1024,F=128,H=512.
// Base: v7's PROVEN protocol (XCD-local groups via HW_REG_XCC_ID, LDS-resident
// [U;W]^T bf16 weights, plain bf16 h dbuf + packed 128B/group flag line,
// relaxed sc0 agent loads/stores; v9's tagged words reverted - replay-diverged).
// New structure:
//  - UNIT-SPLIT: wave w computes full K=640 for its 4 units (v7 tile w) ->
//    no R staging, no reduce, ZERO __syncthreads in the step loop.
//  - CHUNKED ARRIVAL CONSUMPTION: h consumed in 4 chunks of 128 units;
//    chunk c gated by slot flags 8c..8c+7 only (ballot test on one line load);
//    chunk order staggered per wave; straggler wait overlaps useful MFMAs.
//  - BARRIER-FREE PUBLISH JOIN: per-wave vmcnt(0) drain -> lane0 bumps a
//    monotonic LDS counter -> 4th joiner stores the slot flag. Flag(t+1)
//    transitively implies that CU finished reading buf[t&1] (reuse-safe).
// 256 wgs x 256 thr, 82KB LDS -> exactly 1 wg/CU (XCD pigeonhole intact).

#define S_ 1024
#define F_ 128
#define H_ 512
#define G4_ 2048
#define KH 16           // h@U K-steps (512/32)
#define LDKS 640        // shorts per LDS weight row (k dim)
#define HB (64 * H_)    // one h buffer: 64 rows x 512 units (bf16)

typedef __attribute__((ext_vector_type(8))) short short8;  // 8 x bf16
typedef __attribute__((ext_vector_type(4))) float f32x4;
typedef unsigned long long ull;

__device__ __forceinline__ unsigned short f2bf(float f) {
  union { float f; unsigned u; } v; v.f = f;
  unsigned u = v.u + 0x7fffu + ((v.u >> 16) & 1u);   // RNE
  return (unsigned short)(u >> 16);
}

__device__ __forceinline__ short8 pack2(f32x4 a, f32x4 b) {
  short8 r;
#pragma unroll
  for (int i = 0; i < 4; ++i) r[i] = (short)f2bf(a[i]);
#pragma unroll
  for (int i = 0; i < 4; ++i) r[4 + i] = (short)f2bf(b[i]);
  return r;
}

// swizzled short-index into V (validated v5-v8)
__device__ __forceinline__ int swz(int cc, int k) {
  return (cc * LDKS + k) ^ ((cc & 7) << 3);
}

__global__ __launch_bounds__(256, 1) void lstm_pers(
    const float* __restrict__ x, const float* __restrict__ W,
    const float* __restrict__ U, const float* __restrict__ bias,
    float* __restrict__ out, unsigned int* ws_sync, unsigned short* hbuf) {

  __shared__ unsigned short V[64 * LDKS];   // 81920 B
  __shared__ int meta[2];
  __shared__ unsigned join_ctr;             // monotonic: 4 adds per step

  const int tid  = threadIdx.x;
  const int w    = tid >> 6;           // wave 0..3 (owns units u0+4w..+3)
  const int lane = tid & 63;
  const int l15  = lane & 15;
  const int l4   = lane >> 4;
  const int koff = l4 * 8;

  // ---- physical XCD id + slot claim (robust group formation) ----
  if (tid == 0) {
    unsigned int xcc;
    asm volatile("s_getreg_b32 %0, hwreg(20, 0, 4)" : "=s"(xcc));  // HW_REG_XCC_ID
    xcc &= 7;
    unsigned sv = atomicAdd(ws_sync + xcc * 32, 1u);   // 128B-spaced ctrs
    meta[0] = (int)xcc;
    meta[1] = (int)(sv & 31);
    join_ctr = 0u;
  }
  __syncthreads();
  const int xcc  = meta[0];
  const int slot = meta[1];

  unsigned int* gline = ws_sync + 256 + xcc * 32;   // this group's 128B flag line

  const int u0    = slot * 16;       // 16 units per wg
  const int bbase = xcc * 8;         // 8 batch rows per group

  // ---- LDS fill (identical decomposition to v5-v8) ----
  for (int idx = tid; idx < (64 * LDKS) / 4; idx += 256) {
    const int q4   = idx & 15;
    const int k    = idx >> 4;                // 0..639
    const int gate = q4 & 3;
    const int ul0  = (q4 >> 2) * 4;           // 0,4,8,12
    const int col  = gate * H_ + u0 + ul0;
    const float* src = (k < H_) ? (U + (size_t)k * G4_ + col)
                                : (W + (size_t)(k - H_) * G4_ + col);
    const f32x4 v4 = *(const f32x4*)src;
#pragma unroll
    for (int q = 0; q < 4; ++q) {
      const int ul = ul0 + q;
      const int cc = (ul >> 2) * 16 + (ul & 3) * 4 + gate;
      V[swz(cc, k)] = f2bf(v4[q]);
    }
  }

  // wave w's gate bias: unit = u0 + w*4 + l4, reg r = gate r
  float bias_r[4];
#pragma unroll
  for (int g = 0; g < 4; ++g) bias_r[g] = bias[g * H_ + u0 + w * 4 + l4];

  __syncthreads();   // LDS weights ready; last barrier in the kernel

  const int brow = bbase + (l15 & 7);   // rows duplicated for l15>=8
  const float* xrow = x + (size_t)brow * S_ * F_ + koff;
  const unsigned short* hrow0 = hbuf + (size_t)brow * H_ + koff;
  const int myunit = u0 + w * 4 + l4;
  const int vrow   = w * 16 + l15;      // this wave's A-frag LDS row

  float cst = 0.f;                      // c-state of (brow, myunit)

  // preload x(0): all 4 x K-steps for this wave
  f32x4 xa[4], xb[4];
#pragma unroll
  for (int q = 0; q < 4; ++q) {
    xa[q] = *(const f32x4*)(xrow + q * 32);
    xb[q] = *(const f32x4*)(xrow + q * 32 + 4);
  }

  for (int t = 0; t < S_; ++t) {
    f32x4 acc[4];
#pragma unroll
    for (int q = 0; q < 4; ++q) { acc[q][0]=0.f; acc[q][1]=0.f; acc[q][2]=0.f; acc[q][3]=0.f; }

    // ---- x @ W (4 K-steps, h-independent; hides chunk-0 wait) ----
#pragma unroll
    for (int q = 0; q < 4; ++q) {
      const short8 bx = pack2(xa[q], xb[q]);
      const short8 a  = *(const short8*)&V[swz(vrow, (KH + q) * 32 + koff)];
      acc[q] = __builtin_amdgcn_mfma_f32_16x16x32_bf16(a, bx, acc[q], 0, 0, 0);
    }

    // ---- issue x(t+1) loads; complete under the chunk loop ----
    {
      const int tn = (t + 1 < S_) ? t + 1 : t;
      const float* xt = xrow + (size_t)tn * F_;
#pragma unroll
      for (int q = 0; q < 4; ++q) {
        xa[q] = *(const f32x4*)(xt + q * 32);
        xb[q] = *(const f32x4*)(xt + q * 32 + 4);
      }
    }

    // ---- h(t-1) in 4 chunks of 128 units, consumed as producers arrive ----
    if (t > 0) {
      const unsigned tgt = (unsigned)t;
      const unsigned short* hr = hrow0 + (size_t)(t & 1) * HB;
#pragma unroll
      for (int ci = 0; ci < 4; ++ci) {
        const int c = (w + ci) & 3;            // staggered chunk order
        // poll: chunk c ready when slot flags 8c..8c+7 all >= t
        while (true) {
          const unsigned fl = __hip_atomic_load(gline + (lane & 31),
                                                __ATOMIC_RELAXED, __HIP_MEMORY_SCOPE_AGENT);
          ull m = __ballot((int)(fl >= tgt));
          m &= (m >> 32);
          if (((m >> (8 * c)) & 0xFFull) == 0xFFull) break;
        }
        asm volatile("" ::: "memory");         // keep h loads below the poll
#pragma unroll
        for (int i = 0; i < 4; ++i) {
          const int ks = 4 * c + i;
          union { ull u[2]; short8 s; } bb;
          const ull* hq = (const ull*)(hr + ks * 32);
          bb.u[0] = __hip_atomic_load(hq,     __ATOMIC_RELAXED, __HIP_MEMORY_SCOPE_AGENT);
          bb.u[1] = __hip_atomic_load(hq + 1, __ATOMIC_RELAXED, __HIP_MEMORY_SCOPE_AGENT);
          const short8 a = *(const short8*)&V[swz(vrow, ks * 32 + koff)];
          acc[ci] = __builtin_amdgcn_mfma_f32_16x16x32_bf16(a, bb.s, acc[ci], 0, 0, 0);
        }
      }
    }

    // ---- gates: reg r = gate r of this lane's (row, unit) ----
    f32x4 z;
#pragma unroll
    for (int g = 0; g < 4; ++g)
      z[g] = bias_r[g] + acc[0][g] + acc[1][g] + acc[2][g] + acc[3][g];

    const float ig = 1.f / (1.f + __expf(-z[0]));
    const float fg = 1.f / (1.f + __expf(-z[1]));
    const float gg = fmaxf(z[2], 0.f);             // relu candidate
    const float og = 1.f / (1.f + __expf(-z[3]));
    const float cn = fg * cst + ig * gg;
    cst = cn;
    const float hv = og * fmaxf(cn, 0.f);          // relu output activation

    // ---- publish own h slice; barrier-free join via LDS counter ----
    if (l15 < 8)
      hbuf[(size_t)((t + 1) & 1) * HB + (size_t)brow * H_ + myunit] = f2bf(hv);
    asm volatile("s_waitcnt vmcnt(0)" ::: "memory");   // MY stores at L2

    if (lane == 0) {
      const unsigned old = atomicAdd(&join_ctr, 1u);
      if (old == 4u * (unsigned)t + 3u)   // 4th joiner of step t
        __hip_atomic_store(gline + slot, (unsigned)(t + 1),
                           __ATOMIC_RELAXED, __HIP_MEMORY_SCOPE_AGENT);
    }

    if (l15 < 8)
      out[((size_t)brow * S_ + t) * H_ + myunit] = hv;   // off the publish path
  }
}

extern "C" void kernel_launch(void* const* d_in, const int* in_sizes, int n_in,
                              void* d_out, int out_size, void* d_ws, size_t ws_size,
                              hipStream_t stream) {
  const float* x = (const float*)d_in[0];
  const float* W = (const float*)d_in[1];
  const float* U = (const float*)d_in[2];
  const float* b = (const float*)d_in[3];
  float* out = (float*)d_out;

  unsigned int*   ws_sync = (unsigned int*)d_ws;                    // ctrs(1KB) + flag lines(1KB)
  unsigned short* hbuf    = (unsigned short*)((char*)d_ws + 32768); // 2 x 64 x 512 bf16 = 128KB

  hipMemsetAsync(d_ws, 0, 32768, stream);   // zero slot ctrs + flags each launch/replay

  lstm_pers<<<dim3(256), dim3(256), 0, stream>>>(x, W, U, b, out, ws_sync, hbuf);
}

// Round 12
// 2790.930 us; speedup vs baseline: 2.9236x; 2.9236x over previous
//
#include <hip/hip_runtime.h>
#include <stdint.h>

// LSTM(relu) persistent kernel v12: B=64,S=1024,F=128,H=512.
// Base = v7 (best passing, 2627us): XCD-local groups via HW_REG_XCC_ID,
// LDS-resident [U;W]^T bf16, 4-wave K-split, per-tile epilogue, packed 128B
// flag line, __hip_atomic AGENT protocol (PROVEN; v11's hand-rolled sc0 loads
// hung: sc0 alone is CU-scope -> stale-L1 infinite spin).
// Three targeted changes, protocol untouched:
//  1. LDS weight stride 640(+XOR swz) -> 648 plain. v1 measured 4.3e7 conflict
//     cycles with 648 vs 8.5e7 with the v5 swizzle - the swizzle DOUBLED
//     conflicts. 648: row stride 324 dwords = 4 mod 32 -> 2-way aliasing (free).
//  2. barrier3 -> LDS join counter: each wave drains ITS h-store (vmcnt(0)),
//     lane0 bumps join_ctr; the 4th joiner (old==4t+3) publishes the flag.
//     Safety: flag issues only after all 4 waves' vmcnt(0) completed (LDS
//     atomic RMW total order); R reuse stays safe via read(t) < b1(t+1) < write(t+1).
//  3. s_sleep(1) backoff in the poll loop: 32 CUs hammer one 128B flag line
//     (reads + 32 stores interleaved, L2 serializes same-line) - back off to
//     cut line pressure ~4-8x at <=64cy detection cost.
// 256 wgs x 256 thr, ~99KB LDS -> exactly 1 wg/CU (XCD pigeonhole intact).

#define S_ 1024
#define F_ 128
#define H_ 512
#define G4_ 2048
#define KH 16           // h@U K-steps (512/32)
#define KDIM 640
#define LDKS 648        // padded LDS stride (shorts): 2-way-only bank aliasing
#define HB (64 * H_)    // one h buffer: 64 rows x 512 units (bf16)

typedef __attribute__((ext_vector_type(8))) short short8;  // 8 x bf16
typedef __attribute__((ext_vector_type(4))) float f32x4;
typedef unsigned long long ull;

__device__ __forceinline__ unsigned short f2bf(float f) {
  union { float f; unsigned u; } v; v.f = f;
  unsigned u = v.u + 0x7fffu + ((v.u >> 16) & 1u);   // RNE
  return (unsigned short)(u >> 16);
}

__device__ __forceinline__ short8 pack2(f32x4 a, f32x4 b) {
  short8 r;
#pragma unroll
  for (int i = 0; i < 4; ++i) r[i] = (short)f2bf(a[i]);
#pragma unroll
  for (int i = 0; i < 4; ++i) r[4 + i] = (short)f2bf(b[i]);
  return r;
}

__global__ __launch_bounds__(256, 1) void lstm_pers(
    const float* __restrict__ x, const float* __restrict__ W,
    const float* __restrict__ U, const float* __restrict__ bias,
    float* __restrict__ out, unsigned int* ws_sync, unsigned short* hbuf) {

  __shared__ unsigned short V[64 * LDKS];   // 82944 B
  __shared__ f32x4 R[4][4][64];             // 16384 B partial staging
  __shared__ int meta[2];
  __shared__ unsigned join_ctr;             // monotonic: 4 adds per step

  const int tid  = threadIdx.x;
  const int w    = tid >> 6;           // wave 0..3 (k-steps 4w..4w+3; tile w)
  const int lane = tid & 63;
  const int l15  = lane & 15;
  const int l4   = lane >> 4;
  const int koff = l4 * 8;

  // ---- physical XCD id + slot claim (robust group formation) ----
  if (tid == 0) {
    unsigned int xcc;
    asm volatile("s_getreg_b32 %0, hwreg(20, 0, 4)" : "=s"(xcc));  // HW_REG_XCC_ID
    xcc &= 7;
    unsigned sv = atomicAdd(ws_sync + xcc * 32, 1u);   // 128B-spaced ctrs
    meta[0] = (int)xcc;
    meta[1] = (int)(sv & 31);
    join_ctr = 0u;
  }
  __syncthreads();
  const int xcc  = meta[0];
  const int slot = meta[1];

  // flags: ONE 128B line per group, 4B per slot (v7 layout)
  unsigned int* gline  = ws_sync + 256 + xcc * 32;
  unsigned int* myflag = gline + slot;
  unsigned int* pollp  = gline + (lane & 31);

  const int u0    = slot * 16;       // 16 units per wg
  const int bbase = xcc * 8;         // 8 batch rows per group

  // ---- LDS fill: V[cc][k] = bf16(M[k][zcol]); cc = (ul>>2)*16+(ul&3)*4+gate ----
  for (int idx = tid; idx < (64 * KDIM) / 4; idx += 256) {
    const int q4   = idx & 15;
    const int k    = idx >> 4;                // 0..639
    const int gate = q4 & 3;
    const int ul0  = (q4 >> 2) * 4;           // 0,4,8,12
    const int col  = gate * H_ + u0 + ul0;
    const float* src = (k < H_) ? (U + (size_t)k * G4_ + col)
                                : (W + (size_t)(k - H_) * G4_ + col);
    const f32x4 v4 = *(const f32x4*)src;
#pragma unroll
    for (int q = 0; q < 4; ++q) {
      const int ul = ul0 + q;
      const int cc = (ul >> 2) * 16 + (ul & 3) * 4 + gate;
      V[cc * LDKS + k] = f2bf(v4[q]);
    }
  }

  // wave w's gate bias for tile w: unit = u0 + w*4 + l4
  float bias_r[4];
#pragma unroll
  for (int g = 0; g < 4; ++g) bias_r[g] = bias[g * H_ + u0 + w * 4 + l4];

  __syncthreads();

  const int brow = bbase + (l15 & 7);   // rows duplicated for l15>=8
  const float* xrow = x + (size_t)brow * S_ * F_ + koff + w * 32;
  const unsigned short* hrow0 = hbuf + (size_t)brow * H_ + koff;
  const int myunit = u0 + w * 4 + l4;   // this lane's (row,unit) in tile w

  float cst = 0.f;                      // c-state of (brow, myunit)

  // preload x(0) slice for this wave
  f32x4 xa = *(const f32x4*)(xrow);
  f32x4 xb = *(const f32x4*)(xrow + 4);

  for (int t = 0; t < S_; ++t) {
    // ---- x @ W first (h-independent): hides poll latency below ----
    f32x4 acc[4];
#pragma unroll
    for (int tl = 0; tl < 4; ++tl) { acc[tl][0]=0.f; acc[tl][1]=0.f; acc[tl][2]=0.f; acc[tl][3]=0.f; }
    {
      const short8 bx = pack2(xa, xb);
      const int k0 = (KH + w) * 32 + koff;
#pragma unroll
      for (int tl = 0; tl < 4; ++tl) {
        const short8 a = *(const short8*)&V[(tl * 16 + l15) * LDKS + k0];
        acc[tl] = __builtin_amdgcn_mfma_f32_16x16x32_bf16(a, bx, acc[tl], 0, 0, 0);
      }
    }

    // ---- issue x(t+1) loads now; they complete under h@U ----
    {
      const int tn = (t + 1 < S_) ? t + 1 : t;
      const float* xt = xrow + (size_t)tn * F_;
      xa = *(const f32x4*)(xt);
      xb = *(const f32x4*)(xt + 4);
    }

    // ---- wave 0 polls this group's flag line (proven AGENT loads),
    //      with s_sleep backoff to de-contend the hot line ----
    if (t > 0 && w == 0) {
      const unsigned tgt = (unsigned)t;
      while (true) {
        const unsigned v = __hip_atomic_load(pollp, __ATOMIC_RELAXED, __HIP_MEMORY_SCOPE_AGENT);
        if (__all((int)(v >= tgt))) break;
        __builtin_amdgcn_s_sleep(1);
      }
    }
    __syncthreads();   // barrier1: h(t-1) safe for all waves

    // ---- my 4 h B-frags (k-steps 4w..4w+3) + h@U ----
    if (t > 0) {
      const unsigned short* hr = hrow0 + (size_t)(t & 1) * HB;
      short8 bh[4];
#pragma unroll
      for (int i = 0; i < 4; ++i) {
        union { ull u[2]; short8 s; } bb;
        const ull* hq = (const ull*)(hr + (4 * w + i) * 32);
        bb.u[0] = __hip_atomic_load(hq,     __ATOMIC_RELAXED, __HIP_MEMORY_SCOPE_AGENT);
        bb.u[1] = __hip_atomic_load(hq + 1, __ATOMIC_RELAXED, __HIP_MEMORY_SCOPE_AGENT);
        bh[i] = bb.s;
      }
#pragma unroll
      for (int i = 0; i < 4; ++i) {
        const int k0 = (4 * w + i) * 32 + koff;
#pragma unroll
        for (int tl = 0; tl < 4; ++tl) {
          const short8 a = *(const short8*)&V[(tl * 16 + l15) * LDKS + k0];
          acc[tl] = __builtin_amdgcn_mfma_f32_16x16x32_bf16(a, bh[i], acc[tl], 0, 0, 0);
        }
      }
    }

    // ---- stage partials; barrier2; wave w reduces ITS tile ----
#pragma unroll
    for (int tl = 0; tl < 4; ++tl) R[w][tl][lane] = acc[tl];
    __syncthreads();
    // single-buffered R safe: reads(t) precede b1(t+1); writes(t+1) follow it.

    f32x4 z;
    {
      const f32x4 r0 = R[0][w][lane], r1 = R[1][w][lane],
                  r2 = R[2][w][lane], r3 = R[3][w][lane];
#pragma unroll
      for (int g = 0; g < 4; ++g)
        z[g] = bias_r[g] + r0[g] + r1[g] + r2[g] + r3[g];
    }

    // ---- gates for (brow, myunit) ----
    const float ig = 1.f / (1.f + __expf(-z[0]));
    const float fg = 1.f / (1.f + __expf(-z[1]));
    const float gg = fmaxf(z[2], 0.f);             // relu candidate
    const float og = 1.f / (1.f + __expf(-z[3]));
    const float cn = fg * cst + ig * gg;
    cst = cn;
    const float hv = og * fmaxf(cn, 0.f);          // relu output activation

    // ---- publish: h store; per-wave drain; LDS join; 4th joiner flags ----
    if (l15 < 8)
      hbuf[(size_t)((t + 1) & 1) * HB + (size_t)brow * H_ + myunit] = f2bf(hv);
    asm volatile("s_waitcnt vmcnt(0)" ::: "memory");   // MY h slice acked in L2

    if (lane == 0) {
      const unsigned old = atomicAdd(&join_ctr, 1u);
      if (old == 4u * (unsigned)t + 3u)   // last-draining wave of step t
        __hip_atomic_store(myflag, (unsigned)(t + 1),
                           __ATOMIC_RELAXED, __HIP_MEMORY_SCOPE_AGENT);
    }

    if (l15 < 8)
      out[((size_t)brow * S_ + t) * H_ + myunit] = hv;   // off the publish path
  }
}

extern "C" void kernel_launch(void* const* d_in, const int* in_sizes, int n_in,
                              void* d_out, int out_size, void* d_ws, size_t ws_size,
                              hipStream_t stream) {
  const float* x = (const float*)d_in[0];
  const float* W = (const float*)d_in[1];
  const float* U = (const float*)d_in[2];
  const float* b = (const float*)d_in[3];
  float* out = (float*)d_out;

  unsigned int*   ws_sync = (unsigned int*)d_ws;                    // ctrs(1KB) + flag line(1KB)
  unsigned short* hbuf    = (unsigned short*)((char*)d_ws + 32768); // 2 x 64 x 512 bf16 = 128KB

  hipMemsetAsync(d_ws, 0, 32768, stream);   // zero slot ctrs + flags each launch/replay

  lstm_pers<<<dim3(256), dim3(256), 0, stream>>>(x, W, U, b, out, ws_sync, hbuf);
}

// Round 13
// 2715.959 us; speedup vs baseline: 3.0043x; 1.0276x over previous
//
#include <hip/hip_runtime.h>
#include <stdint.h>

// LSTM(relu) persistent kernel v13: B=64,S=1024,F=128,H=512.
// Structure: v7/v12 (XCD-local groups via HW_REG_XCC_ID, LDS-resident [U;W]^T,
// 4-wave K-split, per-tile epilogue). Sync REPLACED by sign-bit-tagged h:
//   h >= 0 always (sigmoid*relu) -> bf16 sign bit is free. Producer stores
//   h halfword with sign = marker((t>>1)&1 ^ 1); consumer spin-loads exactly
//   its needed h words (u64 AGENT loads, per-halfword marker check) ->
//   THE POLL IS THE DATA. 1 L3 hop on the critical path (was: drain + flag
//   + poll + load = 3-4 hops). Initial zeros have marker 0 = invalid.
//   Generation safety: buffer parity + alternating marker distinguishes t
//   from t-2; monotone coherence-point visibility excludes older gens.
//   Anti-runahead (overwrite of a gen still being read would deadlock a
//   marker-waiter): per-wg epoch posted after reads; wave0 snapshots the
//   128B epoch line at step top and gates all>=t-1 pre-barrier (1-step
//   slack -> normally zero wait).
// One __syncthreads per step (R staging, double-buffered).
// Consumer dependency degree: wave w needs only slots 8w..8w+7 (8 wgs).
// 256 wgs x 256 thr, ~116KB LDS -> exactly 1 wg/CU (XCD pigeonhole intact).

#define S_ 1024
#define F_ 128
#define H_ 512
#define G4_ 2048
#define KH 16           // h@U K-steps (512/32)
#define KDIM 640
#define LDKS 648        // padded LDS stride (shorts)
#define HB (64 * H_)    // one h buffer: 64 rows x 512 units (bf16, sign=marker)
#define SMASK 0x8000800080008000ull
#define VMASK 0x7FFF7FFF7FFF7FFFull

typedef __attribute__((ext_vector_type(8))) short short8;  // 8 x bf16
typedef __attribute__((ext_vector_type(4))) float f32x4;
typedef unsigned long long ull;

__device__ __forceinline__ unsigned short f2bf(float f) {
  union { float f; unsigned u; } v; v.f = f;
  unsigned u = v.u + 0x7fffu + ((v.u >> 16) & 1u);   // RNE
  return (unsigned short)(u >> 16);
}

__device__ __forceinline__ short8 pack2(f32x4 a, f32x4 b) {
  short8 r;
#pragma unroll
  for (int i = 0; i < 4; ++i) r[i] = (short)f2bf(a[i]);
#pragma unroll
  for (int i = 0; i < 4; ++i) r[4 + i] = (short)f2bf(b[i]);
  return r;
}

__global__ __launch_bounds__(256, 1) void lstm_pers(
    const float* __restrict__ x, const float* __restrict__ W,
    const float* __restrict__ U, const float* __restrict__ bias,
    float* __restrict__ out, unsigned int* ws_sync, unsigned short* hbuf) {

  __shared__ unsigned short V[64 * LDKS];   // 82944 B
  __shared__ f32x4 R[2][4][4][64];          // 32768 B partial staging (dbuf)
  __shared__ int meta[2];

  const int tid  = threadIdx.x;
  const int w    = tid >> 6;           // wave 0..3 (k-steps 4w..4w+3; tile w)
  const int lane = tid & 63;
  const int l15  = lane & 15;
  const int l4   = lane >> 4;
  const int koff = l4 * 8;

  // ---- physical XCD id + slot claim (robust group formation) ----
  if (tid == 0) {
    unsigned int xcc;
    asm volatile("s_getreg_b32 %0, hwreg(20, 0, 4)" : "=s"(xcc));  // HW_REG_XCC_ID
    xcc &= 7;
    unsigned sv = atomicAdd(ws_sync + xcc * 32, 1u);   // 128B-spaced ctrs
    meta[0] = (int)xcc;
    meta[1] = (int)(sv & 31);
  }
  __syncthreads();
  const int xcc  = meta[0];
  const int slot = meta[1];

  // epoch line: ONE 128B line per group, 4B per slot
  unsigned int* eline = ws_sync + 256 + xcc * 32;
  unsigned int* myep  = eline + slot;
  unsigned int* epp   = eline + (lane & 31);

  const int u0    = slot * 16;       // 16 units per wg
  const int bbase = xcc * 8;         // 8 batch rows per group

  // ---- LDS fill: V[cc][k] = bf16(M[k][zcol]); cc = (ul>>2)*16+(ul&3)*4+gate ----
  for (int idx = tid; idx < (64 * KDIM) / 4; idx += 256) {
    const int q4   = idx & 15;
    const int k    = idx >> 4;                // 0..639
    const int gate = q4 & 3;
    const int ul0  = (q4 >> 2) * 4;           // 0,4,8,12
    const int col  = gate * H_ + u0 + ul0;
    const float* src = (k < H_) ? (U + (size_t)k * G4_ + col)
                                : (W + (size_t)(k - H_) * G4_ + col);
    const f32x4 v4 = *(const f32x4*)src;
#pragma unroll
    for (int q = 0; q < 4; ++q) {
      const int ul = ul0 + q;
      const int cc = (ul >> 2) * 16 + (ul & 3) * 4 + gate;
      V[cc * LDKS + k] = f2bf(v4[q]);
    }
  }

  // wave w's gate bias for tile w: unit = u0 + w*4 + l4
  float bias_r[4];
#pragma unroll
  for (int g = 0; g < 4; ++g) bias_r[g] = bias[g * H_ + u0 + w * 4 + l4];

  __syncthreads();

  const int brow = bbase + (l15 & 7);   // rows duplicated for l15>=8
  const float* xrow = x + (size_t)brow * S_ * F_ + koff + w * 32;
  const unsigned short* hrow0 = hbuf + (size_t)brow * H_ + koff;
  const int myunit = u0 + w * 4 + l4;   // this lane's (row,unit) in tile w

  float cst = 0.f;                      // c-state of (brow, myunit)

  // preload x(0) slice for this wave
  f32x4 xa = *(const f32x4*)(xrow);
  f32x4 xb = *(const f32x4*)(xrow + 4);

  for (int t = 0; t < S_; ++t) {
    // ---- wave 0: early epoch snapshot (has all of MFMA time to land) ----
    unsigned ev = 0xFFFFFFFFu;
    if (w == 0 && t >= 2)
      ev = __hip_atomic_load(epp, __ATOMIC_RELAXED, __HIP_MEMORY_SCOPE_AGENT);

    // ---- x @ W first (h-independent) ----
    f32x4 acc[4];
#pragma unroll
    for (int tl = 0; tl < 4; ++tl) { acc[tl][0]=0.f; acc[tl][1]=0.f; acc[tl][2]=0.f; acc[tl][3]=0.f; }
    {
      const short8 bx = pack2(xa, xb);
      const int k0 = (KH + w) * 32 + koff;
#pragma unroll
      for (int tl = 0; tl < 4; ++tl) {
        const short8 a = *(const short8*)&V[(tl * 16 + l15) * LDKS + k0];
        acc[tl] = __builtin_amdgcn_mfma_f32_16x16x32_bf16(a, bx, acc[tl], 0, 0, 0);
      }
    }

    // ---- issue x(t+1) loads now; they complete under h@U ----
    {
      const int tn = (t + 1 < S_) ? t + 1 : t;
      const float* xt = xrow + (size_t)tn * F_;
      xa = *(const f32x4*)(xt);
      xb = *(const f32x4*)(xt + 4);
    }

    // ---- per-wave tagged data-poll of MY 4 k-chunks (8 producer wgs) ----
    if (t > 0) {
      const ull expm = (((((t - 1) >> 1) & 1) ^ 1) ? SMASK : 0ull);
      const unsigned short* hr = hrow0 + (size_t)(t & 1) * HB;
      const ull* q0 = (const ull*)(hr + (4 * w + 0) * 32);
      const ull* q1 = (const ull*)(hr + (4 * w + 1) * 32);
      const ull* q2 = (const ull*)(hr + (4 * w + 2) * 32);
      const ull* q3 = (const ull*)(hr + (4 * w + 3) * 32);
      ull v0, v1, v2, v3, v4, v5, v6, v7;
      while (true) {
        v0 = __hip_atomic_load(q0,     __ATOMIC_RELAXED, __HIP_MEMORY_SCOPE_AGENT);
        v1 = __hip_atomic_load(q0 + 1, __ATOMIC_RELAXED, __HIP_MEMORY_SCOPE_AGENT);
        v2 = __hip_atomic_load(q1,     __ATOMIC_RELAXED, __HIP_MEMORY_SCOPE_AGENT);
        v3 = __hip_atomic_load(q1 + 1, __ATOMIC_RELAXED, __HIP_MEMORY_SCOPE_AGENT);
        v4 = __hip_atomic_load(q2,     __ATOMIC_RELAXED, __HIP_MEMORY_SCOPE_AGENT);
        v5 = __hip_atomic_load(q2 + 1, __ATOMIC_RELAXED, __HIP_MEMORY_SCOPE_AGENT);
        v6 = __hip_atomic_load(q3,     __ATOMIC_RELAXED, __HIP_MEMORY_SCOPE_AGENT);
        v7 = __hip_atomic_load(q3 + 1, __ATOMIC_RELAXED, __HIP_MEMORY_SCOPE_AGENT);
        const bool ok = ((v0 & SMASK) == expm) & ((v1 & SMASK) == expm) &
                        ((v2 & SMASK) == expm) & ((v3 & SMASK) == expm) &
                        ((v4 & SMASK) == expm) & ((v5 & SMASK) == expm) &
                        ((v6 & SMASK) == expm) & ((v7 & SMASK) == expm);
        if (__all((int)ok)) break;
      }
      // strip markers -> B-frags -> h@U MFMAs
      union { ull u[2]; short8 s; } b0, b1, b2, b3;
      b0.u[0] = v0 & VMASK; b0.u[1] = v1 & VMASK;
      b1.u[0] = v2 & VMASK; b1.u[1] = v3 & VMASK;
      b2.u[0] = v4 & VMASK; b2.u[1] = v5 & VMASK;
      b3.u[0] = v6 & VMASK; b3.u[1] = v7 & VMASK;
      const short8 bh[4] = {b0.s, b1.s, b2.s, b3.s};
#pragma unroll
      for (int i = 0; i < 4; ++i) {
        const int k0 = (4 * w + i) * 32 + koff;
#pragma unroll
        for (int tl = 0; tl < 4; ++tl) {
          const short8 a = *(const short8*)&V[(tl * 16 + l15) * LDKS + k0];
          acc[tl] = __builtin_amdgcn_mfma_f32_16x16x32_bf16(a, bh[i], acc[tl], 0, 0, 0);
        }
      }
    }

    // ---- stage partials (dbuf); epoch gate (wave 0); ONE barrier ----
    const int p = t & 1;
#pragma unroll
    for (int tl = 0; tl < 4; ++tl) R[p][w][tl][lane] = acc[tl];

    if (w == 0 && t >= 2) {
      const unsigned tgt = (unsigned)(t - 1);
      while (!__all((int)(ev >= tgt)))
        ev = __hip_atomic_load(epp, __ATOMIC_RELAXED, __HIP_MEMORY_SCOPE_AGENT);
    }
    __syncthreads();
    // R[p] reuse at t+2 safe: read(t) < barrier(t+1) < write(t+2).
    // Epoch gate pre-barrier -> ALL waves' h-stores below are overwrite-safe.

    // ---- post epoch: this wg finished reading h(t-1) ----
    if (w == 1 && lane == 0)
      __hip_atomic_store(myep, (unsigned)t, __ATOMIC_RELAXED, __HIP_MEMORY_SCOPE_AGENT);

    // ---- wave w reduces ITS tile; gates ----
    f32x4 z;
    {
      const f32x4 r0 = R[p][0][w][lane], r1 = R[p][1][w][lane],
                  r2 = R[p][2][w][lane], r3 = R[p][3][w][lane];
#pragma unroll
      for (int g = 0; g < 4; ++g)
        z[g] = bias_r[g] + r0[g] + r1[g] + r2[g] + r3[g];
    }

    const float ig = 1.f / (1.f + __expf(-z[0]));
    const float fg = 1.f / (1.f + __expf(-z[1]));
    const float gg = fmaxf(z[2], 0.f);             // relu candidate
    const float og = 1.f / (1.f + __expf(-z[3]));
    const float cn = fg * cst + ig * gg;
    cst = cn;
    const float hv = og * fmaxf(cn, 0.f);          // relu output activation (>= 0)

    // ---- publish: single tagged store IS the sync (sign = marker(t)) ----
    if (l15 < 8) {
      const unsigned short sm =
          (unsigned short)(((((unsigned)t >> 1) & 1u) ^ 1u) << 15);
      __hip_atomic_store(&hbuf[(size_t)((t + 1) & 1) * HB + (size_t)brow * H_ + myunit],
                         (unsigned short)(f2bf(hv) | sm),
                         __ATOMIC_RELAXED, __HIP_MEMORY_SCOPE_AGENT);
      out[((size_t)brow * S_ + t) * H_ + myunit] = hv;   // off the publish path
    }
  }
}

extern "C" void kernel_launch(void* const* d_in, const int* in_sizes, int n_in,
                              void* d_out, int out_size, void* d_ws, size_t ws_size,
                              hipStream_t stream) {
  const float* x = (const float*)d_in[0];
  const float* W = (const float*)d_in[1];
  const float* U = (const float*)d_in[2];
  const float* b = (const float*)d_in[3];
  float* out = (float*)d_out;

  unsigned int*   ws_sync = (unsigned int*)d_ws;                    // ctrs(1KB) + epoch lines(1KB)
  unsigned short* hbuf    = (unsigned short*)((char*)d_ws + 32768); // 2 x 64 x 512 bf16 = 128KB

  // zero ctrs + epochs + BOTH tagged h buffers (markers must start invalid).
  // 160KB total = the footprint proven safe in v5-v8.
  hipMemsetAsync(d_ws, 0, 32768 + 2 * HB * sizeof(unsigned short), stream);

  lstm_pers<<<dim3(256), dim3(256), 0, stream>>>(x, W, U, b, out, ws_sync, hbuf);
}